// Round 1
// baseline (4209.536 us; speedup 1.0000x reference)
//
#include <hip/hip_runtime.h>

#define NN 100000
#define NE 1600000
#define HID 128
#define HEADS 4
#define CH 32
#define IN_DIM 257

// ---- monotone float<->uint encoding for atomicMax on signed floats ----
__device__ __forceinline__ unsigned encf(float f) {
    unsigned u = __float_as_uint(f);
    return u ^ ((u & 0x80000000u) ? 0xFFFFFFFFu : 0x80000000u);
}
__device__ __forceinline__ float decf(unsigned u) {
    unsigned b = (u & 0x80000000u) ? (u ^ 0x80000000u) : ~u;
    return __uint_as_float(b);
}

// ---- node projection: XS[N,128] = X[N,K] @ W[K,128] (fp32) ----
// block: 64 nodes x 128 cols; 256 threads; thread = 16 nodes x 2 cols
__global__ __launch_bounds__(256) void node_proj(const float* __restrict__ X,
                                                 const float* __restrict__ W,
                                                 float* __restrict__ XS,
                                                 int K, int nN) {
    __shared__ float xt[64][68];
    int tid = threadIdx.x;
    int block0 = blockIdx.x * 64;
    int c0 = (tid & 63) * 2;
    int mg = tid >> 6;  // 0..3, wave id
    float acc[16][2];
#pragma unroll
    for (int m = 0; m < 16; ++m) { acc[m][0] = 0.f; acc[m][1] = 0.f; }

    for (int k0 = 0; k0 < K; k0 += 64) {
        int kc = min(64, K - k0);
        for (int idx = tid; idx < 64 * 64; idx += 256) {
            int m = idx >> 6, kk = idx & 63;
            int node = block0 + m;
            float v = 0.f;
            if (kk < kc && node < nN) v = X[(long long)node * K + k0 + kk];
            xt[m][kk] = v;
        }
        __syncthreads();
#pragma unroll 1
        for (int kk = 0; kk < 64; kk += 4) {
            float2 w[4];
#pragma unroll
            for (int q = 0; q < 4; ++q) {
                int k = k0 + kk + q;
                w[q] = (k < K) ? *(const float2*)&W[k * HID + c0] : make_float2(0.f, 0.f);
            }
#pragma unroll
            for (int m = 0; m < 16; ++m) {
                float4 xv = *(const float4*)&xt[mg * 16 + m][kk];
                acc[m][0] += xv.x * w[0].x; acc[m][1] += xv.x * w[0].y;
                acc[m][0] += xv.y * w[1].x; acc[m][1] += xv.y * w[1].y;
                acc[m][0] += xv.z * w[2].x; acc[m][1] += xv.z * w[2].y;
                acc[m][0] += xv.w * w[3].x; acc[m][1] += xv.w * w[3].y;
            }
        }
        __syncthreads();
    }
#pragma unroll
    for (int m = 0; m < 16; ++m) {
        int node = block0 + mg * 16 + m;
        if (node < nN) *(float2*)&XS[node * HID + c0] = make_float2(acc[m][0], acc[m][1]);
    }
}

// ---- per-node attention scalars: a_src/a_dst [N,4] ----
__global__ __launch_bounds__(256) void node_att(const float* __restrict__ XS,
                                                const float* __restrict__ att_src,
                                                const float* __restrict__ att_dst,
                                                float* __restrict__ asrc,
                                                float* __restrict__ adst) {
    int i = blockIdx.x * 256 + threadIdx.x;
    if (i >= NN * HEADS) return;
    int n = i >> 2, h = i & 3;
    const float4* xp = (const float4*)&XS[n * HID + h * CH];
    const float4* ap = (const float4*)&att_src[h * CH];
    const float4* bp = (const float4*)&att_dst[h * CH];
    float s = 0.f, d = 0.f;
#pragma unroll
    for (int q = 0; q < 8; ++q) {
        float4 v = xp[q], a = ap[q], b = bp[q];
        s += v.x * a.x + v.y * a.y + v.z * a.z + v.w * a.w;
        d += v.x * b.x + v.y * b.y + v.z * b.z + v.w * b.w;
    }
    asrc[i] = s;
    adst[i] = d;
}

// ---- ve[d,h] = sum_c We[d, h*CH+c] * att_edge[h,c]  (8x4) ----
__global__ void compute_ve(const float* __restrict__ We,
                           const float* __restrict__ att_edge,
                           float* __restrict__ ve) {
    int i = threadIdx.x;
    if (i >= 32) return;
    int d = i >> 2, h = i & 3;
    float s = 0.f;
    for (int c = 0; c < CH; ++c) s += We[d * HID + h * CH + c] * att_edge[h * CH + c];
    ve[i] = s;
}

// ---- pass1: raw alpha (leaky) per edge/head; atomicMax into amax[dst] ----
__global__ __launch_bounds__(256) void edge_pass1(const int* __restrict__ ei,
                                                  const float* __restrict__ eattr,
                                                  const float* __restrict__ asrc,
                                                  const float* __restrict__ adst,
                                                  const float* __restrict__ ve,
                                                  float* __restrict__ alphaE,
                                                  unsigned* __restrict__ amax) {
    __shared__ float ves[32];
    if (threadIdx.x < 32) ves[threadIdx.x] = ve[threadIdx.x];
    __syncthreads();
    int e = blockIdx.x * 256 + threadIdx.x;
    if (e >= NE) return;
    int s = ei[e], d = ei[NE + e];
    float4 ea0 = *(const float4*)&eattr[e * 8];
    float4 ea1 = *(const float4*)&eattr[e * 8 + 4];
    float eav[8] = {ea0.x, ea0.y, ea0.z, ea0.w, ea1.x, ea1.y, ea1.z, ea1.w};
    float4 as4 = *(const float4*)&asrc[s * 4];
    float4 ad4 = *(const float4*)&adst[d * 4];
    float asv[4] = {as4.x, as4.y, as4.z, as4.w};
    float adv[4] = {ad4.x, ad4.y, ad4.z, ad4.w};
    float al[4];
#pragma unroll
    for (int h = 0; h < 4; ++h) {
        float ae = 0.f;
#pragma unroll
        for (int dd = 0; dd < 8; ++dd) ae += eav[dd] * ves[dd * 4 + h];
        float a = asv[h] + adv[h] + ae;
        a = (a > 0.f) ? a : 0.2f * a;
        al[h] = a;
        atomicMax(&amax[d * 4 + h], encf(a));
    }
    *(float4*)&alphaE[e * 4] = make_float4(al[0], al[1], al[2], al[3]);
}

// ---- pass2: p = exp(alpha - amax[dst]); denom[dst] += p ----
__global__ __launch_bounds__(256) void edge_pass2(const int* __restrict__ ei,
                                                  float* __restrict__ alphaE,
                                                  const unsigned* __restrict__ amax,
                                                  float* __restrict__ denom) {
    int e = blockIdx.x * 256 + threadIdx.x;
    if (e >= NE) return;
    int d = ei[NE + e];
    float4 al = *(const float4*)&alphaE[e * 4];
    uint4 mu = *(const uint4*)&amax[d * 4];
    float p0 = expf(al.x - decf(mu.x));
    float p1 = expf(al.y - decf(mu.y));
    float p2 = expf(al.z - decf(mu.z));
    float p3 = expf(al.w - decf(mu.w));
    *(float4*)&alphaE[e * 4] = make_float4(p0, p1, p2, p3);
    atomicAdd(&denom[d * 4 + 0], p0);
    atomicAdd(&denom[d * 4 + 1], p1);
    atomicAdd(&denom[d * 4 + 2], p2);
    atomicAdd(&denom[d * 4 + 3], p3);
}

// ---- pass3: OUT[dst] += xs[src] * (p / (denom[dst]+eps)); one wave per edge ----
__global__ __launch_bounds__(256) void edge_pass3(const int* __restrict__ ei,
                                                  const float* __restrict__ alphaE,
                                                  const float* __restrict__ denom,
                                                  const float* __restrict__ XS,
                                                  float* __restrict__ OUT) {
    int wid = threadIdx.x >> 6, lane = threadIdx.x & 63;
    int e = blockIdx.x * 4 + wid;
    if (e >= NE) return;
    int s = ei[e], d = ei[NE + e];
    int h = lane >> 4;
    float p = alphaE[e * 4 + h];
    float den = denom[d * 4 + h];
    float w = p / (den + 1e-16f);
    float2 xv = *(const float2*)&XS[s * HID + lane * 2];
    atomicAdd(&OUT[d * HID + lane * 2], xv.x * w);
    atomicAdd(&OUT[d * HID + lane * 2 + 1], xv.y * w);
}

// ---- bias + relu (elementwise, float4) ----
__global__ __launch_bounds__(256) void bias_relu(const float* __restrict__ ACC,
                                                 const float* __restrict__ bias,
                                                 float* __restrict__ OUT) {
    int i = blockIdx.x * 256 + threadIdx.x;
    if (i >= NN * (HID / 4)) return;
    float4 v = *(const float4*)&ACC[i * 4];
    int c = (i & 31) * 4;
    float4 b = *(const float4*)&bias[c];
    v.x = fmaxf(v.x + b.x, 0.f);
    v.y = fmaxf(v.y + b.y, 0.f);
    v.z = fmaxf(v.z + b.z, 0.f);
    v.w = fmaxf(v.w + b.w, 0.f);
    *(float4*)&OUT[i * 4] = v;
}

// ---- pooling: per-block LDS table of [64][128] sums + counts, flush with atomics ----
#define POOL_CHUNK 512
__global__ __launch_bounds__(256) void pool_kernel(const float* __restrict__ H,
                                                   const int* __restrict__ batch,
                                                   float* __restrict__ pooled,
                                                   float* __restrict__ counts) {
    __shared__ float tab[64 * HID];
    __shared__ float cnt[64];
    int tid = threadIdx.x;
    int n0 = blockIdx.x * POOL_CHUNK;
    int nmax = min(POOL_CHUNK, NN - n0);
    for (int i = tid; i < 64 * HID; i += 256) tab[i] = 0.f;
    if (tid < 64) cnt[tid] = 0.f;
    __syncthreads();
    for (int i = tid; i < nmax * HID; i += 256) {
        int n = n0 + (i >> 7), c = i & 127;
        int g = batch[n];
        atomicAdd(&tab[g * HID + c], H[(long long)n * HID + c]);
    }
    for (int n = tid; n < nmax; n += 256) atomicAdd(&cnt[batch[n0 + n]], 1.f);
    __syncthreads();
    int gmin = batch[n0], gmax = batch[n0 + nmax - 1];
    int ng = gmax - gmin + 1;
    for (int i = tid; i < ng * HID; i += 256) {
        int g = gmin + (i >> 7), c = i & 127;
        atomicAdd(&pooled[g * HID + c], tab[g * HID + c]);
    }
    if (tid < ng) atomicAdd(&counts[gmin + tid], cnt[gmin + tid]);
}

// ---- classifier: per-graph mean -> relu(fc1) -> fc2 ----
__global__ __launch_bounds__(64) void classifier(const float* __restrict__ pooled,
                                                 const float* __restrict__ counts,
                                                 const float* __restrict__ Wc1,
                                                 const float* __restrict__ bc1,
                                                 const float* __restrict__ Wc2,
                                                 const float* __restrict__ bc2,
                                                 float* __restrict__ out) {
    __shared__ float pl[HID];
    __shared__ float z[64];
    int g = blockIdx.x, t = threadIdx.x;
    float inv = 1.f / fmaxf(counts[g], 1.f);
    pl[t] = pooled[g * HID + t] * inv;
    pl[t + 64] = pooled[g * HID + 64 + t] * inv;
    __syncthreads();
    float a = bc1[t];
    for (int k = 0; k < HID; ++k) a += pl[k] * Wc1[k * 64 + t];
    z[t] = fmaxf(a, 0.f);
    __syncthreads();
    if (t < 2) {
        float o = bc2[t];
        for (int j = 0; j < 64; ++j) o += z[j] * Wc2[j * 2 + t];
        out[g * 2 + t] = o;
    }
}

extern "C" void kernel_launch(void* const* d_in, const int* in_sizes, int n_in,
                              void* d_out, int out_size, void* d_ws, size_t ws_size,
                              hipStream_t stream) {
    const float* x = (const float*)d_in[0];
    const int* ei = (const int*)d_in[1];
    const float* eattr = (const float*)d_in[2];
    const int* batch = (const int*)d_in[3];
    const float* W1 = (const float*)d_in[4];
    const float* att_src1 = (const float*)d_in[5];
    const float* att_dst1 = (const float*)d_in[6];
    const float* We1 = (const float*)d_in[7];
    const float* att_edge1 = (const float*)d_in[8];
    const float* b1 = (const float*)d_in[9];
    const float* W2 = (const float*)d_in[10];
    const float* att_src2 = (const float*)d_in[11];
    const float* att_dst2 = (const float*)d_in[12];
    const float* We2 = (const float*)d_in[13];
    const float* att_edge2 = (const float*)d_in[14];
    const float* b2 = (const float*)d_in[15];
    const float* Wc1 = (const float*)d_in[16];
    const float* bc1 = (const float*)d_in[17];
    const float* Wc2 = (const float*)d_in[18];
    const float* bc2 = (const float*)d_in[19];
    float* out = (float*)d_out;

    // workspace layout
    float* A = (float*)d_ws;                       // xs buffer [N,128]
    float* B = A + (size_t)NN * HID;               // h / acc buffer [N,128]
    float* asrc = B + (size_t)NN * HID;            // [N,4]
    float* adst = asrc + (size_t)NN * 4;           // [N,4]
    unsigned* amax = (unsigned*)(adst + (size_t)NN * 4);  // [N,4]
    float* denom = (float*)(amax + (size_t)NN * 4);       // [N,4]
    float* alphaE = denom + (size_t)NN * 4;        // [E,4]
    float* ve = alphaE + (size_t)NE * 4;           // [32]
    float* pooled = ve + 32;                       // [64,128]
    float* counts = pooled + 64 * HID;             // [64]

    int gProj = (NN + 63) / 64;
    int gNA = (NN * 4 + 255) / 256;
    int gE = (NE + 255) / 256;
    int gE3 = (NE + 3) / 4;
    int gBR = (NN * (HID / 4) + 255) / 256;

    // ===== layer 1 =====
    hipMemsetAsync(amax, 0, (size_t)NN * 4 * sizeof(unsigned), stream);
    hipMemsetAsync(denom, 0, (size_t)NN * 4 * sizeof(float), stream);
    hipMemsetAsync(B, 0, (size_t)NN * HID * sizeof(float), stream);
    compute_ve<<<1, 32, 0, stream>>>(We1, att_edge1, ve);
    node_proj<<<gProj, 256, 0, stream>>>(x, W1, A, IN_DIM, NN);
    node_att<<<gNA, 256, 0, stream>>>(A, att_src1, att_dst1, asrc, adst);
    edge_pass1<<<gE, 256, 0, stream>>>(ei, eattr, asrc, adst, ve, alphaE, amax);
    edge_pass2<<<gE, 256, 0, stream>>>(ei, alphaE, amax, denom);
    edge_pass3<<<gE3, 256, 0, stream>>>(ei, alphaE, denom, A, B);
    bias_relu<<<gBR, 256, 0, stream>>>(B, b1, B);  // B = h1

    // ===== layer 2 =====
    hipMemsetAsync(amax, 0, (size_t)NN * 4 * sizeof(unsigned), stream);
    hipMemsetAsync(denom, 0, (size_t)NN * 4 * sizeof(float), stream);
    compute_ve<<<1, 32, 0, stream>>>(We2, att_edge2, ve);
    node_proj<<<gProj, 256, 0, stream>>>(B, W2, A, HID, NN);  // A = xs2
    node_att<<<gNA, 256, 0, stream>>>(A, att_src2, att_dst2, asrc, adst);
    hipMemsetAsync(B, 0, (size_t)NN * HID * sizeof(float), stream);  // B free after proj
    edge_pass1<<<gE, 256, 0, stream>>>(ei, eattr, asrc, adst, ve, alphaE, amax);
    edge_pass2<<<gE, 256, 0, stream>>>(ei, alphaE, amax, denom);
    edge_pass3<<<gE3, 256, 0, stream>>>(ei, alphaE, denom, A, B);
    bias_relu<<<gBR, 256, 0, stream>>>(B, b2, B);  // B = h2

    // ===== pool + classify =====
    hipMemsetAsync(pooled, 0, (64 * HID + 64) * sizeof(float), stream);
    pool_kernel<<<(NN + POOL_CHUNK - 1) / POOL_CHUNK, 256, 0, stream>>>(B, batch, pooled, counts);
    classifier<<<64, 64, 0, stream>>>(pooled, counts, Wc1, bc1, Wc2, bc2, out);
}

// Round 2
// 1144.968 us; speedup vs baseline: 3.6766x; 3.6766x over previous
//
#include <hip/hip_runtime.h>

#define NN 100000
#define NE 1600000
#define HID 128
#define HEADS 4
#define CH 32
#define IN_DIM 257

// ==================== node projection GEMM (fp32, VALU) ====================
// block: 64 nodes x 128 cols; 256 threads; thread = 16 nodes x 2 cols
__global__ __launch_bounds__(256) void node_proj(const float* __restrict__ X,
                                                 const float* __restrict__ W,
                                                 float* __restrict__ XS,
                                                 int K, int nN) {
    __shared__ float xt[64][68];
    int tid = threadIdx.x;
    int block0 = blockIdx.x * 64;
    int c0 = (tid & 63) * 2;
    int mg = tid >> 6;  // 0..3, wave id
    float acc[16][2];
#pragma unroll
    for (int m = 0; m < 16; ++m) { acc[m][0] = 0.f; acc[m][1] = 0.f; }

    for (int k0 = 0; k0 < K; k0 += 64) {
        int kc = min(64, K - k0);
        for (int idx = tid; idx < 64 * 64; idx += 256) {
            int m = idx >> 6, kk = idx & 63;
            int node = block0 + m;
            float v = 0.f;
            if (kk < kc && node < nN) v = X[(long long)node * K + k0 + kk];
            xt[m][kk] = v;
        }
        __syncthreads();
#pragma unroll 1
        for (int kk = 0; kk < 64; kk += 4) {
            float2 w[4];
#pragma unroll
            for (int q = 0; q < 4; ++q) {
                int k = k0 + kk + q;
                w[q] = (k < K) ? *(const float2*)&W[k * HID + c0] : make_float2(0.f, 0.f);
            }
#pragma unroll
            for (int m = 0; m < 16; ++m) {
                float4 xv = *(const float4*)&xt[mg * 16 + m][kk];
                acc[m][0] += xv.x * w[0].x; acc[m][1] += xv.x * w[0].y;
                acc[m][0] += xv.y * w[1].x; acc[m][1] += xv.y * w[1].y;
                acc[m][0] += xv.z * w[2].x; acc[m][1] += xv.z * w[2].y;
                acc[m][0] += xv.w * w[3].x; acc[m][1] += xv.w * w[3].y;
            }
        }
        __syncthreads();
    }
#pragma unroll
    for (int m = 0; m < 16; ++m) {
        int node = block0 + mg * 16 + m;
        if (node < nN) *(float2*)&XS[node * HID + c0] = make_float2(acc[m][0], acc[m][1]);
    }
}

// ==================== per-node attention scalars ====================
__global__ __launch_bounds__(256) void node_att(const float* __restrict__ XS,
                                                const float* __restrict__ att_src,
                                                const float* __restrict__ att_dst,
                                                float* __restrict__ asrc,
                                                float* __restrict__ adst) {
    int i = blockIdx.x * 256 + threadIdx.x;
    if (i >= NN * HEADS) return;
    int n = i >> 2, h = i & 3;
    const float4* xp = (const float4*)&XS[n * HID + h * CH];
    const float4* ap = (const float4*)&att_src[h * CH];
    const float4* bp = (const float4*)&att_dst[h * CH];
    float s = 0.f, d = 0.f;
#pragma unroll
    for (int q = 0; q < 8; ++q) {
        float4 v = xp[q], a = ap[q], b = bp[q];
        s += v.x * a.x + v.y * a.y + v.z * a.z + v.w * a.w;
        d += v.x * b.x + v.y * b.y + v.z * b.z + v.w * b.w;
    }
    asrc[i] = s;
    adst[i] = d;
}

// ---- ve[d,h] = sum_c We[d, h*CH+c] * att_edge[h,c]  (8x4) ----
__global__ void compute_ve(const float* __restrict__ We,
                           const float* __restrict__ att_edge,
                           float* __restrict__ ve) {
    int i = threadIdx.x;
    if (i >= 32) return;
    int d = i >> 2, h = i & 3;
    float s = 0.f;
    for (int c = 0; c < CH; ++c) s += We[d * HID + h * CH + c] * att_edge[h * CH + c];
    ve[i] = s;
}

// ==================== CSR build ====================
__global__ __launch_bounds__(256) void k_deg(const int* __restrict__ ei, int* __restrict__ deg) {
    int e = blockIdx.x * 256 + threadIdx.x;
    if (e < NE) atomicAdd(&deg[ei[NE + e]], 1);
}

// 1024 elems per block (256 threads x 4); writes exclusive local scan + block sum
__global__ __launch_bounds__(256) void scan_local(const int* __restrict__ deg,
                                                  int* __restrict__ startv,
                                                  int* __restrict__ bsum) {
    __shared__ int sh[256];
    int t = threadIdx.x;
    int base = blockIdx.x * 1024 + t * 4;
    int v0 = 0, v1 = 0, v2 = 0, v3 = 0;
    if (base + 0 < NN) v0 = deg[base + 0];
    if (base + 1 < NN) v1 = deg[base + 1];
    if (base + 2 < NN) v2 = deg[base + 2];
    if (base + 3 < NN) v3 = deg[base + 3];
    int s1 = v0 + v1, s2 = s1 + v2, s3 = s2 + v3;
    sh[t] = s3;
    __syncthreads();
    for (int off = 1; off < 256; off <<= 1) {
        int x = (t >= off) ? sh[t - off] : 0;
        __syncthreads();
        sh[t] += x;
        __syncthreads();
    }
    int thOff = sh[t] - s3;  // exclusive
    if (base + 0 < NN) startv[base + 0] = thOff;
    if (base + 1 < NN) startv[base + 1] = thOff + v0;
    if (base + 2 < NN) startv[base + 2] = thOff + s1;
    if (base + 3 < NN) startv[base + 3] = thOff + s2;
    if (t == 255) bsum[blockIdx.x] = sh[255];
}

__global__ __launch_bounds__(256) void scan_bsum(int* __restrict__ bsum, int nb) {
    __shared__ int sh[256];
    int t = threadIdx.x;
    int v = (t < nb) ? bsum[t] : 0;
    sh[t] = v;
    __syncthreads();
    for (int off = 1; off < 256; off <<= 1) {
        int x = (t >= off) ? sh[t - off] : 0;
        __syncthreads();
        sh[t] += x;
        __syncthreads();
    }
    if (t < nb) bsum[t] = sh[t] - v;  // exclusive
}

__global__ __launch_bounds__(256) void scan_add(int* __restrict__ startv,
                                                const int* __restrict__ bsum) {
    int i = blockIdx.x * 256 + threadIdx.x;
    if (i < NN) startv[i] += bsum[i >> 10];
}

__global__ __launch_bounds__(256) void k_scatter(const int* __restrict__ ei,
                                                 const int* __restrict__ startv,
                                                 int* __restrict__ cursor,
                                                 int* __restrict__ eperm,
                                                 int* __restrict__ srcperm) {
    int e = blockIdx.x * 256 + threadIdx.x;
    if (e >= NE) return;
    int d = ei[NE + e];
    int pos = startv[d] + atomicAdd(&cursor[d], 1);
    eperm[pos] = e;
    srcperm[pos] = ei[e];
}

// ==================== pass1: raw leaky alpha, written in PERMUTED order ====================
__global__ __launch_bounds__(256) void edge_pass1(const int* __restrict__ ei,
                                                  const float* __restrict__ eattr,
                                                  const float* __restrict__ asrc,
                                                  const float* __restrict__ adst,
                                                  const float* __restrict__ ve,
                                                  const int* __restrict__ eperm,
                                                  float* __restrict__ alphaP) {
    __shared__ float ves[32];
    if (threadIdx.x < 32) ves[threadIdx.x] = ve[threadIdx.x];
    __syncthreads();
    int idx = blockIdx.x * 256 + threadIdx.x;
    if (idx >= NE) return;
    int e = eperm[idx];
    int s = ei[e], d = ei[NE + e];
    float4 ea0 = *(const float4*)&eattr[e * 8];
    float4 ea1 = *(const float4*)&eattr[e * 8 + 4];
    float eav[8] = {ea0.x, ea0.y, ea0.z, ea0.w, ea1.x, ea1.y, ea1.z, ea1.w};
    float4 as4 = *(const float4*)&asrc[s * 4];
    float4 ad4 = *(const float4*)&adst[d * 4];
    float asv[4] = {as4.x, as4.y, as4.z, as4.w};
    float adv[4] = {ad4.x, ad4.y, ad4.z, ad4.w};
    float al[4];
#pragma unroll
    for (int h = 0; h < 4; ++h) {
        float ae = 0.f;
#pragma unroll
        for (int dd = 0; dd < 8; ++dd) ae += eav[dd] * ves[dd * 4 + h];
        float a = asv[h] + adv[h] + ae;
        al[h] = (a > 0.f) ? a : 0.2f * a;
    }
    *(float4*)&alphaP[idx * 4] = make_float4(al[0], al[1], al[2], al[3]);
}

// ==================== gather: softmax + weighted aggregate + bias + relu ====================
// one wave per dst node; lane -> 2 channels; head = lane>>4
__global__ __launch_bounds__(256) void gat_gather(const int* __restrict__ startv,
                                                  const int* __restrict__ deg,
                                                  const int* __restrict__ srcperm,
                                                  const float* __restrict__ alphaP,
                                                  const float* __restrict__ XS,
                                                  const float* __restrict__ bias,
                                                  float* __restrict__ OUT) {
    int wid = blockIdx.x * 4 + (threadIdx.x >> 6);
    if (wid >= NN) return;
    int lane = threadIdx.x & 63;
    int s0 = startv[wid];
    int dg = deg[wid];
    int h = lane >> 4;
    int c0 = lane * 2;

    float m = -1e30f;
    for (int j = 0; j < dg; ++j) {
        float a = alphaP[(size_t)(s0 + j) * 4 + h];
        m = fmaxf(m, a);
    }
    float denom = 0.f, acc0 = 0.f, acc1 = 0.f;
    for (int j = 0; j < dg; ++j) {
        float a = alphaP[(size_t)(s0 + j) * 4 + h];
        int s = srcperm[s0 + j];
        float p = expf(a - m);
        denom += p;
        float2 xv = *(const float2*)&XS[(size_t)s * HID + c0];
        acc0 += p * xv.x;
        acc1 += p * xv.y;
    }
    float inv = 1.f / (denom + 1e-16f);
    float o0 = fmaxf(acc0 * inv + bias[c0], 0.f);
    float o1 = fmaxf(acc1 * inv + bias[c0 + 1], 0.f);
    *(float2*)&OUT[(size_t)wid * HID + c0] = make_float2(o0, o1);
}

// ==================== pooling ====================
#define POOL_CHUNK 512
__global__ __launch_bounds__(256) void pool_kernel(const float* __restrict__ H,
                                                   const int* __restrict__ batch,
                                                   float* __restrict__ pooled,
                                                   float* __restrict__ counts) {
    __shared__ float tab[64 * HID];
    __shared__ float cnt[64];
    int tid = threadIdx.x;
    int n0 = blockIdx.x * POOL_CHUNK;
    int nmax = min(POOL_CHUNK, NN - n0);
    for (int i = tid; i < 64 * HID; i += 256) tab[i] = 0.f;
    if (tid < 64) cnt[tid] = 0.f;
    __syncthreads();
    for (int i = tid; i < nmax * HID; i += 256) {
        int n = n0 + (i >> 7), c = i & 127;
        int g = batch[n];
        atomicAdd(&tab[g * HID + c], H[(long long)n * HID + c]);
    }
    for (int n = tid; n < nmax; n += 256) atomicAdd(&cnt[batch[n0 + n]], 1.f);
    __syncthreads();
    int gmin = batch[n0], gmax = batch[n0 + nmax - 1];
    int ng = gmax - gmin + 1;
    for (int i = tid; i < ng * HID; i += 256) {
        int g = gmin + (i >> 7), c = i & 127;
        atomicAdd(&pooled[g * HID + c], tab[g * HID + c]);
    }
    if (tid < ng) atomicAdd(&counts[gmin + tid], cnt[gmin + tid]);
}

// ==================== classifier ====================
__global__ __launch_bounds__(64) void classifier(const float* __restrict__ pooled,
                                                 const float* __restrict__ counts,
                                                 const float* __restrict__ Wc1,
                                                 const float* __restrict__ bc1,
                                                 const float* __restrict__ Wc2,
                                                 const float* __restrict__ bc2,
                                                 float* __restrict__ out) {
    __shared__ float pl[HID];
    __shared__ float z[64];
    int g = blockIdx.x, t = threadIdx.x;
    float inv = 1.f / fmaxf(counts[g], 1.f);
    pl[t] = pooled[g * HID + t] * inv;
    pl[t + 64] = pooled[g * HID + 64 + t] * inv;
    __syncthreads();
    float a = bc1[t];
    for (int k = 0; k < HID; ++k) a += pl[k] * Wc1[k * 64 + t];
    z[t] = fmaxf(a, 0.f);
    __syncthreads();
    if (t < 2) {
        float o = bc2[t];
        for (int j = 0; j < 64; ++j) o += z[j] * Wc2[j * 2 + t];
        out[g * 2 + t] = o;
    }
}

extern "C" void kernel_launch(void* const* d_in, const int* in_sizes, int n_in,
                              void* d_out, int out_size, void* d_ws, size_t ws_size,
                              hipStream_t stream) {
    const float* x = (const float*)d_in[0];
    const int* ei = (const int*)d_in[1];
    const float* eattr = (const float*)d_in[2];
    const int* batch = (const int*)d_in[3];
    const float* W1 = (const float*)d_in[4];
    const float* att_src1 = (const float*)d_in[5];
    const float* att_dst1 = (const float*)d_in[6];
    const float* We1 = (const float*)d_in[7];
    const float* att_edge1 = (const float*)d_in[8];
    const float* b1 = (const float*)d_in[9];
    const float* W2 = (const float*)d_in[10];
    const float* att_src2 = (const float*)d_in[11];
    const float* att_dst2 = (const float*)d_in[12];
    const float* We2 = (const float*)d_in[13];
    const float* att_edge2 = (const float*)d_in[14];
    const float* b2 = (const float*)d_in[15];
    const float* Wc1 = (const float*)d_in[16];
    const float* bc1 = (const float*)d_in[17];
    const float* Wc2 = (const float*)d_in[18];
    const float* bc2 = (const float*)d_in[19];
    float* out = (float*)d_out;

    // workspace layout (floats then ints)
    float* A = (float*)d_ws;                        // xs buffer [N,128]
    float* B = A + (size_t)NN * HID;                // h buffer [N,128]
    float* asrc = B + (size_t)NN * HID;             // [N,4]
    float* adst = asrc + (size_t)NN * 4;            // [N,4]
    float* alphaP = adst + (size_t)NN * 4;          // [E,4] permuted alpha
    float* ve = alphaP + (size_t)NE * 4;            // [32]
    float* pooled = ve + 32;                        // [64,128]
    float* counts = pooled + 64 * HID;              // [64]
    int* deg = (int*)(counts + 64);                 // [N]
    int* startv = deg + NN;                         // [N]
    int* cursor = startv + NN;                      // [N]
    int* bsum = cursor + NN;                        // [256]
    int* eperm = bsum + 256;                        // [E]
    int* srcperm = eperm + NE;                      // [E]

    int gProj = (NN + 63) / 64;
    int gNA = (NN * 4 + 255) / 256;
    int gE = (NE + 255) / 256;
    int gGat = (NN + 3) / 4;
    int nScanBlk = (NN + 1023) / 1024;  // 98

    // ===== CSR build (once per launch) =====
    hipMemsetAsync(deg, 0, (size_t)NN * sizeof(int), stream);
    hipMemsetAsync(cursor, 0, (size_t)NN * sizeof(int), stream);
    k_deg<<<gE, 256, 0, stream>>>(ei, deg);
    scan_local<<<nScanBlk, 256, 0, stream>>>(deg, startv, bsum);
    scan_bsum<<<1, 256, 0, stream>>>(bsum, nScanBlk);
    scan_add<<<(NN + 255) / 256, 256, 0, stream>>>(startv, bsum);
    k_scatter<<<gE, 256, 0, stream>>>(ei, startv, cursor, eperm, srcperm);

    // ===== layer 1 =====
    compute_ve<<<1, 32, 0, stream>>>(We1, att_edge1, ve);
    node_proj<<<gProj, 256, 0, stream>>>(x, W1, A, IN_DIM, NN);
    node_att<<<gNA, 256, 0, stream>>>(A, att_src1, att_dst1, asrc, adst);
    edge_pass1<<<gE, 256, 0, stream>>>(ei, eattr, asrc, adst, ve, eperm, alphaP);
    gat_gather<<<gGat, 256, 0, stream>>>(startv, deg, srcperm, alphaP, A, b1, B);  // B = h1

    // ===== layer 2 =====
    compute_ve<<<1, 32, 0, stream>>>(We2, att_edge2, ve);
    node_proj<<<gProj, 256, 0, stream>>>(B, W2, A, HID, NN);  // A = xs2
    node_att<<<gNA, 256, 0, stream>>>(A, att_src2, att_dst2, asrc, adst);
    edge_pass1<<<gE, 256, 0, stream>>>(ei, eattr, asrc, adst, ve, eperm, alphaP);
    gat_gather<<<gGat, 256, 0, stream>>>(startv, deg, srcperm, alphaP, A, b2, B);  // B = h2

    // ===== pool + classify =====
    hipMemsetAsync(pooled, 0, (64 * HID + 64) * sizeof(float), stream);
    pool_kernel<<<(NN + POOL_CHUNK - 1) / POOL_CHUNK, 256, 0, stream>>>(B, batch, pooled, counts);
    classifier<<<64, 64, 0, stream>>>(pooled, counts, Wc1, bc1, Wc2, bc2, out);
}

// Round 3
// 958.162 us; speedup vs baseline: 4.3933x; 1.1950x over previous
//
#include <hip/hip_runtime.h>

#define NN 100000
#define NE 1600000
#define HID 128
#define HEADS 4
#define CH 32
#define IN_DIM 257
#define CHK 128  // edges per LDS chunk in gather

// ==================== node projection GEMM (fp32, VALU) ====================
// block: 64 nodes x 128 cols; 256 threads; thread = 16 nodes x 2 cols
__global__ __launch_bounds__(256) void node_proj(const float* __restrict__ X,
                                                 const float* __restrict__ W,
                                                 float* __restrict__ XS,
                                                 int K, int nN) {
    __shared__ float xt[64][68];
    int tid = threadIdx.x;
    int block0 = blockIdx.x * 64;
    int c0 = (tid & 63) * 2;
    int mg = tid >> 6;  // 0..3, wave id
    float acc[16][2];
#pragma unroll
    for (int m = 0; m < 16; ++m) { acc[m][0] = 0.f; acc[m][1] = 0.f; }

    for (int k0 = 0; k0 < K; k0 += 64) {
        int kc = min(64, K - k0);
        for (int idx = tid; idx < 64 * 64; idx += 256) {
            int m = idx >> 6, kk = idx & 63;
            int node = block0 + m;
            float v = 0.f;
            if (kk < kc && node < nN) v = X[(long long)node * K + k0 + kk];
            xt[m][kk] = v;
        }
        __syncthreads();
#pragma unroll 1
        for (int kk = 0; kk < 64; kk += 4) {
            float2 w[4];
#pragma unroll
            for (int q = 0; q < 4; ++q) {
                int k = k0 + kk + q;
                w[q] = (k < K) ? *(const float2*)&W[k * HID + c0] : make_float2(0.f, 0.f);
            }
#pragma unroll
            for (int m = 0; m < 16; ++m) {
                float4 xv = *(const float4*)&xt[mg * 16 + m][kk];
                acc[m][0] += xv.x * w[0].x; acc[m][1] += xv.x * w[0].y;
                acc[m][0] += xv.y * w[1].x; acc[m][1] += xv.y * w[1].y;
                acc[m][0] += xv.z * w[2].x; acc[m][1] += xv.z * w[2].y;
                acc[m][0] += xv.w * w[3].x; acc[m][1] += xv.w * w[3].y;
            }
        }
        __syncthreads();
    }
#pragma unroll
    for (int m = 0; m < 16; ++m) {
        int node = block0 + mg * 16 + m;
        if (node < nN) *(float2*)&XS[node * HID + c0] = make_float2(acc[m][0], acc[m][1]);
    }
}

// ==================== per-node attention scalars ====================
__global__ __launch_bounds__(256) void node_att(const float* __restrict__ XS,
                                                const float* __restrict__ att_src,
                                                const float* __restrict__ att_dst,
                                                float* __restrict__ asrc,
                                                float* __restrict__ adst) {
    int i = blockIdx.x * 256 + threadIdx.x;
    if (i >= NN * HEADS) return;
    int n = i >> 2, h = i & 3;
    const float4* xp = (const float4*)&XS[n * HID + h * CH];
    const float4* ap = (const float4*)&att_src[h * CH];
    const float4* bp = (const float4*)&att_dst[h * CH];
    float s = 0.f, d = 0.f;
#pragma unroll
    for (int q = 0; q < 8; ++q) {
        float4 v = xp[q], a = ap[q], b = bp[q];
        s += v.x * a.x + v.y * a.y + v.z * a.z + v.w * a.w;
        d += v.x * b.x + v.y * b.y + v.z * b.z + v.w * b.w;
    }
    asrc[i] = s;
    adst[i] = d;
}

// ---- ve[d,h] = sum_c We[d, h*CH+c] * att_edge[h,c]  (8x4) ----
__global__ void compute_ve(const float* __restrict__ We,
                           const float* __restrict__ att_edge,
                           float* __restrict__ ve) {
    int i = threadIdx.x;
    if (i >= 32) return;
    int d = i >> 2, h = i & 3;
    float s = 0.f;
    for (int c = 0; c < CH; ++c) s += We[d * HID + h * CH + c] * att_edge[h * CH + c];
    ve[i] = s;
}

// ==================== CSR build ====================
__global__ __launch_bounds__(256) void k_deg(const int* __restrict__ ei, int* __restrict__ deg) {
    int e = blockIdx.x * 256 + threadIdx.x;
    if (e < NE) atomicAdd(&deg[ei[NE + e]], 1);
}

// 1024 elems per block (256 threads x 4); writes exclusive local scan + block sum
__global__ __launch_bounds__(256) void scan_local(const int* __restrict__ deg,
                                                  int* __restrict__ startv,
                                                  int* __restrict__ bsum) {
    __shared__ int sh[256];
    int t = threadIdx.x;
    int base = blockIdx.x * 1024 + t * 4;
    int v0 = 0, v1 = 0, v2 = 0, v3 = 0;
    if (base + 0 < NN) v0 = deg[base + 0];
    if (base + 1 < NN) v1 = deg[base + 1];
    if (base + 2 < NN) v2 = deg[base + 2];
    if (base + 3 < NN) v3 = deg[base + 3];
    int s1 = v0 + v1, s2 = s1 + v2, s3 = s2 + v3;
    sh[t] = s3;
    __syncthreads();
    for (int off = 1; off < 256; off <<= 1) {
        int x = (t >= off) ? sh[t - off] : 0;
        __syncthreads();
        sh[t] += x;
        __syncthreads();
    }
    int thOff = sh[t] - s3;  // exclusive
    if (base + 0 < NN) startv[base + 0] = thOff;
    if (base + 1 < NN) startv[base + 1] = thOff + v0;
    if (base + 2 < NN) startv[base + 2] = thOff + s1;
    if (base + 3 < NN) startv[base + 3] = thOff + s2;
    if (t == 255) bsum[blockIdx.x] = sh[255];
}

__global__ __launch_bounds__(256) void scan_bsum(int* __restrict__ bsum, int nb) {
    __shared__ int sh[256];
    int t = threadIdx.x;
    int v = (t < nb) ? bsum[t] : 0;
    sh[t] = v;
    __syncthreads();
    for (int off = 1; off < 256; off <<= 1) {
        int x = (t >= off) ? sh[t - off] : 0;
        __syncthreads();
        sh[t] += x;
        __syncthreads();
    }
    if (t < nb) bsum[t] = sh[t] - v;  // exclusive
}

__global__ __launch_bounds__(256) void scan_add(int* __restrict__ startv,
                                                const int* __restrict__ bsum) {
    int i = blockIdx.x * 256 + threadIdx.x;
    if (i < NN) startv[i] += bsum[i >> 10];
}

__global__ __launch_bounds__(256) void k_scatter(const int* __restrict__ ei,
                                                 const int* __restrict__ startv,
                                                 int* __restrict__ cursor,
                                                 int* __restrict__ eperm,
                                                 int* __restrict__ srcperm) {
    int e = blockIdx.x * 256 + threadIdx.x;
    if (e >= NE) return;
    int d = ei[NE + e];
    int pos = startv[d] + atomicAdd(&cursor[d], 1);
    eperm[pos] = e;
    srcperm[pos] = ei[e];
}

// ==================== pass1: raw leaky alpha, written in PERMUTED order ====================
__global__ __launch_bounds__(256) void edge_pass1(const int* __restrict__ ei,
                                                  const float* __restrict__ eattr,
                                                  const float* __restrict__ asrc,
                                                  const float* __restrict__ adst,
                                                  const float* __restrict__ ve,
                                                  const int* __restrict__ eperm,
                                                  float* __restrict__ alphaP) {
    __shared__ float ves[32];
    if (threadIdx.x < 32) ves[threadIdx.x] = ve[threadIdx.x];
    __syncthreads();
    int idx = blockIdx.x * 256 + threadIdx.x;
    if (idx >= NE) return;
    int e = eperm[idx];
    int s = ei[e], d = ei[NE + e];
    float4 ea0 = *(const float4*)&eattr[e * 8];
    float4 ea1 = *(const float4*)&eattr[e * 8 + 4];
    float eav[8] = {ea0.x, ea0.y, ea0.z, ea0.w, ea1.x, ea1.y, ea1.z, ea1.w};
    float4 as4 = *(const float4*)&asrc[s * 4];
    float4 ad4 = *(const float4*)&adst[d * 4];
    float asv[4] = {as4.x, as4.y, as4.z, as4.w};
    float adv[4] = {ad4.x, ad4.y, ad4.z, ad4.w};
    float al[4];
#pragma unroll
    for (int h = 0; h < 4; ++h) {
        float ae = 0.f;
#pragma unroll
        for (int dd = 0; dd < 8; ++dd) ae += eav[dd] * ves[dd * 4 + h];
        float a = asv[h] + adv[h] + ae;
        al[h] = (a > 0.f) ? a : 0.2f * a;
    }
    *(float4*)&alphaP[idx * 4] = make_float4(al[0], al[1], al[2], al[3]);
}

// ==================== gather v2: LDS-staged segment, pipelined XS gathers ====================
// one wave per dst node (4 waves/block); lane -> 2 channels; head = lane>>4
__global__ __launch_bounds__(256) void gat_gather(const int* __restrict__ startv,
                                                  const int* __restrict__ deg,
                                                  const int* __restrict__ srcperm,
                                                  const float* __restrict__ alphaP,
                                                  const float* __restrict__ XS,
                                                  const float* __restrict__ bias,
                                                  float* __restrict__ OUT) {
    __shared__ float s_al[4][CHK * 4];
    __shared__ int s_src[4][CHK];
    int w = threadIdx.x >> 6;
    int wid = blockIdx.x * 4 + w;
    if (wid >= NN) return;
    int lane = threadIdx.x & 63;
    int s0 = startv[wid];
    int dg = deg[wid];
    int h = lane >> 4;
    int c0 = lane * 2;

    float m = -1e30f;
    float denom = 0.f, acc0 = 0.f, acc1 = 0.f;

    for (int cb = 0; cb < dg; cb += CHK) {
        int cnt = min(CHK, dg - cb);
        // cooperative (wave-synchronous) stage of src + alpha into LDS
        for (int i = lane; i < cnt; i += 64) {
            s_src[w][i] = srcperm[s0 + cb + i];
            *(float4*)&s_al[w][i * 4] = *(const float4*)&alphaP[(size_t)(s0 + cb + i) * 4];
        }
        // sweep 1: chunk max per head (LDS only)
        float mc = -1e30f;
        for (int j = 0; j < cnt; ++j) mc = fmaxf(mc, s_al[w][j * 4 + h]);
        float mn = fmaxf(m, mc);
        float scale = __expf(m - mn);  // 0 on first chunk (m=-1e30)
        denom *= scale; acc0 *= scale; acc1 *= scale;
        m = mn;
        // sweep 2: accumulate, 4 independent XS gathers in flight
        int j = 0;
        for (; j + 3 < cnt; j += 4) {
            int sA = s_src[w][j], sB = s_src[w][j + 1], sC = s_src[w][j + 2], sD = s_src[w][j + 3];
            float aA = s_al[w][j * 4 + h], aB = s_al[w][(j + 1) * 4 + h];
            float aC = s_al[w][(j + 2) * 4 + h], aD = s_al[w][(j + 3) * 4 + h];
            float2 xA = *(const float2*)&XS[(size_t)sA * HID + c0];
            float2 xB = *(const float2*)&XS[(size_t)sB * HID + c0];
            float2 xC = *(const float2*)&XS[(size_t)sC * HID + c0];
            float2 xD = *(const float2*)&XS[(size_t)sD * HID + c0];
            float pA = __expf(aA - m), pB = __expf(aB - m);
            float pC = __expf(aC - m), pD = __expf(aD - m);
            denom += pA + pB + pC + pD;
            acc0 += pA * xA.x + pB * xB.x + pC * xC.x + pD * xD.x;
            acc1 += pA * xA.y + pB * xB.y + pC * xC.y + pD * xD.y;
        }
        for (; j < cnt; ++j) {
            int s = s_src[w][j];
            float a = s_al[w][j * 4 + h];
            float2 xv = *(const float2*)&XS[(size_t)s * HID + c0];
            float p = __expf(a - m);
            denom += p;
            acc0 += p * xv.x;
            acc1 += p * xv.y;
        }
    }
    float inv = 1.f / (denom + 1e-16f);
    float2 bv = *(const float2*)&bias[c0];
    float o0 = fmaxf(acc0 * inv + bv.x, 0.f);
    float o1 = fmaxf(acc1 * inv + bv.y, 0.f);
    *(float2*)&OUT[(size_t)wid * HID + c0] = make_float2(o0, o1);
}

// ==================== pooling ====================
#define POOL_CHUNK 512
__global__ __launch_bounds__(256) void pool_kernel(const float* __restrict__ H,
                                                   const int* __restrict__ batch,
                                                   float* __restrict__ pooled,
                                                   float* __restrict__ counts) {
    __shared__ float tab[64 * HID];
    __shared__ float cnt[64];
    int tid = threadIdx.x;
    int n0 = blockIdx.x * POOL_CHUNK;
    int nmax = min(POOL_CHUNK, NN - n0);
    for (int i = tid; i < 64 * HID; i += 256) tab[i] = 0.f;
    if (tid < 64) cnt[tid] = 0.f;
    __syncthreads();
    for (int i = tid; i < nmax * HID; i += 256) {
        int n = n0 + (i >> 7), c = i & 127;
        int g = batch[n];
        atomicAdd(&tab[g * HID + c], H[(long long)n * HID + c]);
    }
    for (int n = tid; n < nmax; n += 256) atomicAdd(&cnt[batch[n0 + n]], 1.f);
    __syncthreads();
    int gmin = batch[n0], gmax = batch[n0 + nmax - 1];
    int ng = gmax - gmin + 1;
    for (int i = tid; i < ng * HID; i += 256) {
        int g = gmin + (i >> 7), c = i & 127;
        atomicAdd(&pooled[g * HID + c], tab[g * HID + c]);
    }
    if (tid < ng) atomicAdd(&counts[gmin + tid], cnt[gmin + tid]);
}

// ==================== classifier ====================
__global__ __launch_bounds__(64) void classifier(const float* __restrict__ pooled,
                                                 const float* __restrict__ counts,
                                                 const float* __restrict__ Wc1,
                                                 const float* __restrict__ bc1,
                                                 const float* __restrict__ Wc2,
                                                 const float* __restrict__ bc2,
                                                 float* __restrict__ out) {
    __shared__ float pl[HID];
    __shared__ float z[64];
    int g = blockIdx.x, t = threadIdx.x;
    float inv = 1.f / fmaxf(counts[g], 1.f);
    pl[t] = pooled[g * HID + t] * inv;
    pl[t + 64] = pooled[g * HID + 64 + t] * inv;
    __syncthreads();
    float a = bc1[t];
    for (int k = 0; k < HID; ++k) a += pl[k] * Wc1[k * 64 + t];
    z[t] = fmaxf(a, 0.f);
    __syncthreads();
    if (t < 2) {
        float o = bc2[t];
        for (int j = 0; j < 64; ++j) o += z[j] * Wc2[j * 2 + t];
        out[g * 2 + t] = o;
    }
}

extern "C" void kernel_launch(void* const* d_in, const int* in_sizes, int n_in,
                              void* d_out, int out_size, void* d_ws, size_t ws_size,
                              hipStream_t stream) {
    const float* x = (const float*)d_in[0];
    const int* ei = (const int*)d_in[1];
    const float* eattr = (const float*)d_in[2];
    const int* batch = (const int*)d_in[3];
    const float* W1 = (const float*)d_in[4];
    const float* att_src1 = (const float*)d_in[5];
    const float* att_dst1 = (const float*)d_in[6];
    const float* We1 = (const float*)d_in[7];
    const float* att_edge1 = (const float*)d_in[8];
    const float* b1 = (const float*)d_in[9];
    const float* W2 = (const float*)d_in[10];
    const float* att_src2 = (const float*)d_in[11];
    const float* att_dst2 = (const float*)d_in[12];
    const float* We2 = (const float*)d_in[13];
    const float* att_edge2 = (const float*)d_in[14];
    const float* b2 = (const float*)d_in[15];
    const float* Wc1 = (const float*)d_in[16];
    const float* bc1 = (const float*)d_in[17];
    const float* Wc2 = (const float*)d_in[18];
    const float* bc2 = (const float*)d_in[19];
    float* out = (float*)d_out;

    // workspace layout (floats then ints)
    float* A = (float*)d_ws;                        // xs buffer [N,128]
    float* B = A + (size_t)NN * HID;                // h buffer [N,128]
    float* asrc = B + (size_t)NN * HID;             // [N,4]
    float* adst = asrc + (size_t)NN * 4;            // [N,4]
    float* alphaP = adst + (size_t)NN * 4;          // [E,4] permuted alpha
    float* ve = alphaP + (size_t)NE * 4;            // [32]
    float* pooled = ve + 32;                        // [64,128]
    float* counts = pooled + 64 * HID;              // [64]
    int* deg = (int*)(counts + 64);                 // [N]
    int* startv = deg + NN;                         // [N]
    int* cursor = startv + NN;                      // [N]
    int* bsum = cursor + NN;                        // [256]
    int* eperm = bsum + 256;                        // [E]
    int* srcperm = eperm + NE;                      // [E]

    int gProj = (NN + 63) / 64;
    int gNA = (NN * 4 + 255) / 256;
    int gE = (NE + 255) / 256;
    int gGat = (NN + 3) / 4;
    int nScanBlk = (NN + 1023) / 1024;  // 98

    // ===== CSR build (once per launch) =====
    hipMemsetAsync(deg, 0, (size_t)NN * sizeof(int), stream);
    hipMemsetAsync(cursor, 0, (size_t)NN * sizeof(int), stream);
    k_deg<<<gE, 256, 0, stream>>>(ei, deg);
    scan_local<<<nScanBlk, 256, 0, stream>>>(deg, startv, bsum);
    scan_bsum<<<1, 256, 0, stream>>>(bsum, nScanBlk);
    scan_add<<<(NN + 255) / 256, 256, 0, stream>>>(startv, bsum);
    k_scatter<<<gE, 256, 0, stream>>>(ei, startv, cursor, eperm, srcperm);

    // ===== layer 1 =====
    compute_ve<<<1, 32, 0, stream>>>(We1, att_edge1, ve);
    node_proj<<<gProj, 256, 0, stream>>>(x, W1, A, IN_DIM, NN);
    node_att<<<gNA, 256, 0, stream>>>(A, att_src1, att_dst1, asrc, adst);
    edge_pass1<<<gE, 256, 0, stream>>>(ei, eattr, asrc, adst, ve, eperm, alphaP);
    gat_gather<<<gGat, 256, 0, stream>>>(startv, deg, srcperm, alphaP, A, b1, B);  // B = h1

    // ===== layer 2 =====
    compute_ve<<<1, 32, 0, stream>>>(We2, att_edge2, ve);
    node_proj<<<gProj, 256, 0, stream>>>(B, W2, A, HID, NN);  // A = xs2
    node_att<<<gNA, 256, 0, stream>>>(A, att_src2, att_dst2, asrc, adst);
    edge_pass1<<<gE, 256, 0, stream>>>(ei, eattr, asrc, adst, ve, eperm, alphaP);
    gat_gather<<<gGat, 256, 0, stream>>>(startv, deg, srcperm, alphaP, A, b2, B);  // B = h2

    // ===== pool + classify =====
    hipMemsetAsync(pooled, 0, (64 * HID + 64) * sizeof(float), stream);
    pool_kernel<<<(NN + POOL_CHUNK - 1) / POOL_CHUNK, 256, 0, stream>>>(B, batch, pooled, counts);
    classifier<<<64, 64, 0, stream>>>(pooled, counts, Wc1, bc1, Wc2, bc2, out);
}

// Round 4
// 955.972 us; speedup vs baseline: 4.4034x; 1.0023x over previous
//
#include <hip/hip_runtime.h>

#define NN 100000
#define NE 1600000
#define HID 128
#define HEADS 4
#define CH 32
#define IN_DIM 257
#define CHK 128  // edges per LDS chunk in gather

// ==================== fused node projection + attention scalars ====================
// block: 64 nodes x 128 cols; 256 threads; thread = 8 nodes (mg=tid>>5) x 4 cols (cg=tid&31)
// LDS x-tile reads are pure broadcast (all lanes in a col-group read the same address).
// Epilogue: per-head dot with att_src/att_dst + 8-lane shfl reduction -> asrc/adst.
__global__ __launch_bounds__(256) void node_proj_att(const float* __restrict__ X,
                                                     const float* __restrict__ W,
                                                     const float* __restrict__ att_src,
                                                     const float* __restrict__ att_dst,
                                                     float* __restrict__ XS,
                                                     float* __restrict__ asrc,
                                                     float* __restrict__ adst,
                                                     int K, int nN) {
    __shared__ float xt[64][68];
    int tid = threadIdx.x;
    int block0 = blockIdx.x * 64;
    int cg = tid & 31;
    int c0 = cg * 4;
    int mg = tid >> 5;       // 0..7
    int mbase = mg * 8;      // 8 nodes per thread
    float acc[8][4];
#pragma unroll
    for (int m = 0; m < 8; ++m)
#pragma unroll
        for (int c = 0; c < 4; ++c) acc[m][c] = 0.f;

    for (int k0 = 0; k0 < K; k0 += 64) {
        int kc = min(64, K - k0);
        for (int idx = tid; idx < 64 * 64; idx += 256) {
            int m = idx >> 6, kk = idx & 63;
            int node = block0 + m;
            float v = 0.f;
            if (kk < kc && node < nN) v = X[(long long)node * K + k0 + kk];
            xt[m][kk] = v;
        }
        __syncthreads();
#pragma unroll 1
        for (int kk = 0; kk < 64; kk += 4) {
            float4 w0, w1, w2, w3;
            {
                int k = k0 + kk;
                w0 = (k + 0 < K) ? *(const float4*)&W[(k + 0) * HID + c0] : make_float4(0.f, 0.f, 0.f, 0.f);
                w1 = (k + 1 < K) ? *(const float4*)&W[(k + 1) * HID + c0] : make_float4(0.f, 0.f, 0.f, 0.f);
                w2 = (k + 2 < K) ? *(const float4*)&W[(k + 2) * HID + c0] : make_float4(0.f, 0.f, 0.f, 0.f);
                w3 = (k + 3 < K) ? *(const float4*)&W[(k + 3) * HID + c0] : make_float4(0.f, 0.f, 0.f, 0.f);
            }
#pragma unroll
            for (int m = 0; m < 8; ++m) {
                float4 xv = *(const float4*)&xt[mbase + m][kk];
                acc[m][0] += xv.x * w0.x; acc[m][1] += xv.x * w0.y; acc[m][2] += xv.x * w0.z; acc[m][3] += xv.x * w0.w;
                acc[m][0] += xv.y * w1.x; acc[m][1] += xv.y * w1.y; acc[m][2] += xv.y * w1.z; acc[m][3] += xv.y * w1.w;
                acc[m][0] += xv.z * w2.x; acc[m][1] += xv.z * w2.y; acc[m][2] += xv.z * w2.z; acc[m][3] += xv.z * w2.w;
                acc[m][0] += xv.w * w3.x; acc[m][1] += xv.w * w3.y; acc[m][2] += xv.w * w3.z; acc[m][3] += xv.w * w3.w;
            }
        }
        __syncthreads();
    }

    // epilogue: write XS + fused per-head attention dots
    float4 av = *(const float4*)&att_src[c0];
    float4 bv = *(const float4*)&att_dst[c0];
    int h = cg >> 3;  // head = c0/32
#pragma unroll
    for (int m = 0; m < 8; ++m) {
        int node = block0 + mbase + m;
        float s = acc[m][0] * av.x + acc[m][1] * av.y + acc[m][2] * av.z + acc[m][3] * av.w;
        float d = acc[m][0] * bv.x + acc[m][1] * bv.y + acc[m][2] * bv.z + acc[m][3] * bv.w;
        // reduce over the 8 lanes covering this head's 32 channels
        s += __shfl_xor(s, 4); d += __shfl_xor(d, 4);
        s += __shfl_xor(s, 2); d += __shfl_xor(d, 2);
        s += __shfl_xor(s, 1); d += __shfl_xor(d, 1);
        if (node < nN) {
            *(float4*)&XS[(size_t)node * HID + c0] = make_float4(acc[m][0], acc[m][1], acc[m][2], acc[m][3]);
            if ((cg & 7) == 0) {
                asrc[node * 4 + h] = s;
                adst[node * 4 + h] = d;
            }
        }
    }
}

// ---- ve[d,h] = sum_c We[d, h*CH+c] * att_edge[h,c]  (8x4) ----
__global__ void compute_ve(const float* __restrict__ We,
                           const float* __restrict__ att_edge,
                           float* __restrict__ ve) {
    int i = threadIdx.x;
    if (i >= 32) return;
    int d = i >> 2, h = i & 3;
    float s = 0.f;
    for (int c = 0; c < CH; ++c) s += We[d * HID + h * CH + c] * att_edge[h * CH + c];
    ve[i] = s;
}

// ==================== CSR build ====================
__global__ __launch_bounds__(256) void k_deg(const int* __restrict__ ei, int* __restrict__ deg) {
    int e = blockIdx.x * 256 + threadIdx.x;
    if (e < NE) atomicAdd(&deg[ei[NE + e]], 1);
}

// 1024 elems per block (256 threads x 4); writes exclusive local scan + block sum
__global__ __launch_bounds__(256) void scan_local(const int* __restrict__ deg,
                                                  int* __restrict__ startv,
                                                  int* __restrict__ bsum) {
    __shared__ int sh[256];
    int t = threadIdx.x;
    int base = blockIdx.x * 1024 + t * 4;
    int v0 = 0, v1 = 0, v2 = 0, v3 = 0;
    if (base + 0 < NN) v0 = deg[base + 0];
    if (base + 1 < NN) v1 = deg[base + 1];
    if (base + 2 < NN) v2 = deg[base + 2];
    if (base + 3 < NN) v3 = deg[base + 3];
    int s1 = v0 + v1, s2 = s1 + v2, s3 = s2 + v3;
    sh[t] = s3;
    __syncthreads();
    for (int off = 1; off < 256; off <<= 1) {
        int x = (t >= off) ? sh[t - off] : 0;
        __syncthreads();
        sh[t] += x;
        __syncthreads();
    }
    int thOff = sh[t] - s3;  // exclusive
    if (base + 0 < NN) startv[base + 0] = thOff;
    if (base + 1 < NN) startv[base + 1] = thOff + v0;
    if (base + 2 < NN) startv[base + 2] = thOff + s1;
    if (base + 3 < NN) startv[base + 3] = thOff + s2;
    if (t == 255) bsum[blockIdx.x] = sh[255];
}

__global__ __launch_bounds__(256) void scan_bsum(int* __restrict__ bsum, int nb) {
    __shared__ int sh[256];
    int t = threadIdx.x;
    int v = (t < nb) ? bsum[t] : 0;
    sh[t] = v;
    __syncthreads();
    for (int off = 1; off < 256; off <<= 1) {
        int x = (t >= off) ? sh[t - off] : 0;
        __syncthreads();
        sh[t] += x;
        __syncthreads();
    }
    if (t < nb) bsum[t] = sh[t] - v;  // exclusive
}

__global__ __launch_bounds__(256) void scan_add(int* __restrict__ startv,
                                                const int* __restrict__ bsum) {
    int i = blockIdx.x * 256 + threadIdx.x;
    if (i < NN) startv[i] += bsum[i >> 10];
}

__global__ __launch_bounds__(256) void k_scatter(const int* __restrict__ ei,
                                                 const int* __restrict__ startv,
                                                 int* __restrict__ cursor,
                                                 int* __restrict__ eperm,
                                                 int* __restrict__ srcperm) {
    int e = blockIdx.x * 256 + threadIdx.x;
    if (e >= NE) return;
    int d = ei[NE + e];
    int pos = startv[d] + atomicAdd(&cursor[d], 1);
    eperm[pos] = e;
    srcperm[pos] = ei[e];
}

// ==================== pass1: raw leaky alpha, written in PERMUTED order ====================
__global__ __launch_bounds__(256) void edge_pass1(const int* __restrict__ ei,
                                                  const float* __restrict__ eattr,
                                                  const float* __restrict__ asrc,
                                                  const float* __restrict__ adst,
                                                  const float* __restrict__ ve,
                                                  const int* __restrict__ eperm,
                                                  float* __restrict__ alphaP) {
    __shared__ float ves[32];
    if (threadIdx.x < 32) ves[threadIdx.x] = ve[threadIdx.x];
    __syncthreads();
    int idx = blockIdx.x * 256 + threadIdx.x;
    if (idx >= NE) return;
    int e = eperm[idx];
    int s = ei[e], d = ei[NE + e];
    float4 ea0 = *(const float4*)&eattr[e * 8];
    float4 ea1 = *(const float4*)&eattr[e * 8 + 4];
    float eav[8] = {ea0.x, ea0.y, ea0.z, ea0.w, ea1.x, ea1.y, ea1.z, ea1.w};
    float4 as4 = *(const float4*)&asrc[s * 4];
    float4 ad4 = *(const float4*)&adst[d * 4];
    float asv[4] = {as4.x, as4.y, as4.z, as4.w};
    float adv[4] = {ad4.x, ad4.y, ad4.z, ad4.w};
    float al[4];
#pragma unroll
    for (int h = 0; h < 4; ++h) {
        float ae = 0.f;
#pragma unroll
        for (int dd = 0; dd < 8; ++dd) ae += eav[dd] * ves[dd * 4 + h];
        float a = asv[h] + adv[h] + ae;
        al[h] = (a > 0.f) ? a : 0.2f * a;
    }
    *(float4*)&alphaP[idx * 4] = make_float4(al[0], al[1], al[2], al[3]);
}

// ==================== gather: LDS-staged segment, pipelined XS gathers ====================
// one wave per dst node (4 waves/block); lane -> 2 channels; head = lane>>4
__global__ __launch_bounds__(256) void gat_gather(const int* __restrict__ startv,
                                                  const int* __restrict__ deg,
                                                  const int* __restrict__ srcperm,
                                                  const float* __restrict__ alphaP,
                                                  const float* __restrict__ XS,
                                                  const float* __restrict__ bias,
                                                  float* __restrict__ OUT) {
    __shared__ float s_al[4][CHK * 4];
    __shared__ int s_src[4][CHK];
    int w = threadIdx.x >> 6;
    int wid = blockIdx.x * 4 + w;
    if (wid >= NN) return;
    int lane = threadIdx.x & 63;
    int s0 = startv[wid];
    int dg = deg[wid];
    int h = lane >> 4;
    int c0 = lane * 2;

    float m = -1e30f;
    float denom = 0.f, acc0 = 0.f, acc1 = 0.f;

    for (int cb = 0; cb < dg; cb += CHK) {
        int cnt = min(CHK, dg - cb);
        // cooperative (wave-synchronous) stage of src + alpha into LDS
        for (int i = lane; i < cnt; i += 64) {
            s_src[w][i] = srcperm[s0 + cb + i];
            *(float4*)&s_al[w][i * 4] = *(const float4*)&alphaP[(size_t)(s0 + cb + i) * 4];
        }
        // sweep 1: chunk max per head (LDS only)
        float mc = -1e30f;
        for (int j = 0; j < cnt; ++j) mc = fmaxf(mc, s_al[w][j * 4 + h]);
        float mn = fmaxf(m, mc);
        float scale = __expf(m - mn);  // 0 on first chunk (m=-1e30)
        denom *= scale; acc0 *= scale; acc1 *= scale;
        m = mn;
        // sweep 2: accumulate, 4 independent XS gathers in flight
        int j = 0;
        for (; j + 3 < cnt; j += 4) {
            int sA = s_src[w][j], sB = s_src[w][j + 1], sC = s_src[w][j + 2], sD = s_src[w][j + 3];
            float aA = s_al[w][j * 4 + h], aB = s_al[w][(j + 1) * 4 + h];
            float aC = s_al[w][(j + 2) * 4 + h], aD = s_al[w][(j + 3) * 4 + h];
            float2 xA = *(const float2*)&XS[(size_t)sA * HID + c0];
            float2 xB = *(const float2*)&XS[(size_t)sB * HID + c0];
            float2 xC = *(const float2*)&XS[(size_t)sC * HID + c0];
            float2 xD = *(const float2*)&XS[(size_t)sD * HID + c0];
            float pA = __expf(aA - m), pB = __expf(aB - m);
            float pC = __expf(aC - m), pD = __expf(aD - m);
            denom += pA + pB + pC + pD;
            acc0 += pA * xA.x + pB * xB.x + pC * xC.x + pD * xD.x;
            acc1 += pA * xA.y + pB * xB.y + pC * xC.y + pD * xD.y;
        }
        for (; j < cnt; ++j) {
            int s = s_src[w][j];
            float a = s_al[w][j * 4 + h];
            float2 xv = *(const float2*)&XS[(size_t)s * HID + c0];
            float p = __expf(a - m);
            denom += p;
            acc0 += p * xv.x;
            acc1 += p * xv.y;
        }
    }
    float inv = 1.f / (denom + 1e-16f);
    float2 bv = *(const float2*)&bias[c0];
    float o0 = fmaxf(acc0 * inv + bv.x, 0.f);
    float o1 = fmaxf(acc1 * inv + bv.y, 0.f);
    *(float2*)&OUT[(size_t)wid * HID + c0] = make_float2(o0, o1);
}

// ==================== pooling ====================
#define POOL_CHUNK 512
__global__ __launch_bounds__(256) void pool_kernel(const float* __restrict__ H,
                                                   const int* __restrict__ batch,
                                                   float* __restrict__ pooled,
                                                   float* __restrict__ counts) {
    __shared__ float tab[64 * HID];
    __shared__ float cnt[64];
    int tid = threadIdx.x;
    int n0 = blockIdx.x * POOL_CHUNK;
    int nmax = min(POOL_CHUNK, NN - n0);
    for (int i = tid; i < 64 * HID; i += 256) tab[i] = 0.f;
    if (tid < 64) cnt[tid] = 0.f;
    __syncthreads();
    for (int i = tid; i < nmax * HID; i += 256) {
        int n = n0 + (i >> 7), c = i & 127;
        int g = batch[n];
        atomicAdd(&tab[g * HID + c], H[(long long)n * HID + c]);
    }
    for (int n = tid; n < nmax; n += 256) atomicAdd(&cnt[batch[n0 + n]], 1.f);
    __syncthreads();
    int gmin = batch[n0], gmax = batch[n0 + nmax - 1];
    int ng = gmax - gmin + 1;
    for (int i = tid; i < ng * HID; i += 256) {
        int g = gmin + (i >> 7), c = i & 127;
        atomicAdd(&pooled[g * HID + c], tab[g * HID + c]);
    }
    if (tid < ng) atomicAdd(&counts[gmin + tid], cnt[gmin + tid]);
}

// ==================== classifier ====================
__global__ __launch_bounds__(64) void classifier(const float* __restrict__ pooled,
                                                 const float* __restrict__ counts,
                                                 const float* __restrict__ Wc1,
                                                 const float* __restrict__ bc1,
                                                 const float* __restrict__ Wc2,
                                                 const float* __restrict__ bc2,
                                                 float* __restrict__ out) {
    __shared__ float pl[HID];
    __shared__ float z[64];
    int g = blockIdx.x, t = threadIdx.x;
    float inv = 1.f / fmaxf(counts[g], 1.f);
    pl[t] = pooled[g * HID + t] * inv;
    pl[t + 64] = pooled[g * HID + 64 + t] * inv;
    __syncthreads();
    float a = bc1[t];
    for (int k = 0; k < HID; ++k) a += pl[k] * Wc1[k * 64 + t];
    z[t] = fmaxf(a, 0.f);
    __syncthreads();
    if (t < 2) {
        float o = bc2[t];
        for (int j = 0; j < 64; ++j) o += z[j] * Wc2[j * 2 + t];
        out[g * 2 + t] = o;
    }
}

extern "C" void kernel_launch(void* const* d_in, const int* in_sizes, int n_in,
                              void* d_out, int out_size, void* d_ws, size_t ws_size,
                              hipStream_t stream) {
    const float* x = (const float*)d_in[0];
    const int* ei = (const int*)d_in[1];
    const float* eattr = (const float*)d_in[2];
    const int* batch = (const int*)d_in[3];
    const float* W1 = (const float*)d_in[4];
    const float* att_src1 = (const float*)d_in[5];
    const float* att_dst1 = (const float*)d_in[6];
    const float* We1 = (const float*)d_in[7];
    const float* att_edge1 = (const float*)d_in[8];
    const float* b1 = (const float*)d_in[9];
    const float* W2 = (const float*)d_in[10];
    const float* att_src2 = (const float*)d_in[11];
    const float* att_dst2 = (const float*)d_in[12];
    const float* We2 = (const float*)d_in[13];
    const float* att_edge2 = (const float*)d_in[14];
    const float* b2 = (const float*)d_in[15];
    const float* Wc1 = (const float*)d_in[16];
    const float* bc1 = (const float*)d_in[17];
    const float* Wc2 = (const float*)d_in[18];
    const float* bc2 = (const float*)d_in[19];
    float* out = (float*)d_out;

    // workspace layout (floats then ints)
    float* A = (float*)d_ws;                        // xs buffer [N,128]
    float* B = A + (size_t)NN * HID;                // h buffer [N,128]
    float* asrc = B + (size_t)NN * HID;             // [N,4]
    float* adst = asrc + (size_t)NN * 4;            // [N,4]
    float* alphaP = adst + (size_t)NN * 4;          // [E,4] permuted alpha
    float* ve = alphaP + (size_t)NE * 4;            // [32]
    float* pooled = ve + 32;                        // [64,128]
    float* counts = pooled + 64 * HID;              // [64]
    int* deg = (int*)(counts + 64);                 // [N]
    int* startv = deg + NN;                         // [N]
    int* cursor = startv + NN;                      // [N]
    int* bsum = cursor + NN;                        // [256]
    int* eperm = bsum + 256;                        // [E]
    int* srcperm = eperm + NE;                      // [E]

    int gProj = (NN + 63) / 64;
    int gE = (NE + 255) / 256;
    int gGat = (NN + 3) / 4;
    int nScanBlk = (NN + 1023) / 1024;  // 98

    // ===== CSR build (once per launch) =====
    hipMemsetAsync(deg, 0, (size_t)NN * sizeof(int), stream);
    hipMemsetAsync(cursor, 0, (size_t)NN * sizeof(int), stream);
    k_deg<<<gE, 256, 0, stream>>>(ei, deg);
    scan_local<<<nScanBlk, 256, 0, stream>>>(deg, startv, bsum);
    scan_bsum<<<1, 256, 0, stream>>>(bsum, nScanBlk);
    scan_add<<<(NN + 255) / 256, 256, 0, stream>>>(startv, bsum);
    k_scatter<<<gE, 256, 0, stream>>>(ei, startv, cursor, eperm, srcperm);

    // ===== layer 1 =====
    compute_ve<<<1, 32, 0, stream>>>(We1, att_edge1, ve);
    node_proj_att<<<gProj, 256, 0, stream>>>(x, W1, att_src1, att_dst1, A, asrc, adst, IN_DIM, NN);
    edge_pass1<<<gE, 256, 0, stream>>>(ei, eattr, asrc, adst, ve, eperm, alphaP);
    gat_gather<<<gGat, 256, 0, stream>>>(startv, deg, srcperm, alphaP, A, b1, B);  // B = h1

    // ===== layer 2 =====
    compute_ve<<<1, 32, 0, stream>>>(We2, att_edge2, ve);
    node_proj_att<<<gProj, 256, 0, stream>>>(B, W2, att_src2, att_dst2, A, asrc, adst, HID, NN);
    edge_pass1<<<gE, 256, 0, stream>>>(ei, eattr, asrc, adst, ve, eperm, alphaP);
    gat_gather<<<gGat, 256, 0, stream>>>(startv, deg, srcperm, alphaP, A, b2, B);  // B = h2

    // ===== pool + classify =====
    hipMemsetAsync(pooled, 0, (64 * HID + 64) * sizeof(float), stream);
    pool_kernel<<<(NN + POOL_CHUNK - 1) / POOL_CHUNK, 256, 0, stream>>>(B, batch, pooled, counts);
    classifier<<<64, 64, 0, stream>>>(pooled, counts, Wc1, bc1, Wc2, bc2, out);
}